// Round 15
// baseline (361.853 us; speedup 1.0000x reference)
//
#include <hip/hip_runtime.h>
#include <hip/hip_cooperative_groups.h>

namespace cg = cooperative_groups;

#define MAXNB 64
#define CAP   128   // candidate capacity per query (expected ~35, max ~65)
#define GRID  12    // 12^3 cells, cell width 1/12 ~ 0.0833 > r = 0.08
#define NCELL (GRID * GRID * GRID)   // 1728
#define CAPC  40    // bin capacity; Poisson(9.48) P(>=40) ~ 1e-15 -> never hit

// ---------------------------------------------------------------------------
// Single cooperative kernel: {zero cellcnt} sync {bin points} sync
// {scanrank, grid-stride} sync {splits, block 0}. Eliminates 3 dispatch
// boundaries + the memset dispatch. Unlike R8's per-block-retire ticket
// (L1-invalidate storm), fences here are 3 aligned phase barriers.
// All numerics identical to R14: d2 contract-OFF ((dx2+dy2)+dz2), packed
// u64 keys (f32bits(d2)<<32|idx), rank = #smaller keys == top_k(-d2) order.
// ---------------------------------------------------------------------------
__global__ __launch_bounds__(256, 4) void fused_kernel(
    const float* __restrict__ inp, const float* __restrict__ qry,
    int* __restrict__ cellcnt, float4* __restrict__ cells,
    int* __restrict__ cnt, int* __restrict__ nbr, int* __restrict__ rs,
    int n, int m) {
#pragma clang fp contract(off)
  const float R2 = (float)(0.08 * 0.08);
  const float RM = 0.0801f;  // margin 1e-4 >> fp error, << cell slack 0.0033
  cg::grid_group grid = cg::this_grid();

  __shared__ unsigned long long skey[4][CAP];
  __shared__ int sbase[4][9];   // row first-bin base address (elements)
  __shared__ int sn0[4][9];     // row bin0 count
  __shared__ int sn01[4][9];    // row bin0+bin1 count
  __shared__ int sracc[4][9];   // exclusive prefix of row lengths
  __shared__ int souts[4][MAXNB];
  __shared__ int part[256];

  int tid = threadIdx.x;
  int gid = blockIdx.x * 256 + tid;
  int nthreads = gridDim.x * 256;

  // ---- phase 0: zero cell counters ----
  for (int i = gid; i < NCELL; i += nthreads) cellcnt[i] = 0;
  grid.sync();

  // ---- phase 1: bin points into fixed-capacity cells ----
  for (int i = gid; i < n; i += nthreads) {
    float x = inp[3 * i], y = inp[3 * i + 1], z = inp[3 * i + 2];
    int cx = min(GRID - 1, max(0, (int)(x * (float)GRID)));
    int cy = min(GRID - 1, max(0, (int)(y * (float)GRID)));
    int cz = min(GRID - 1, max(0, (int)(z * (float)GRID)));
    int c = (cz * GRID + cy) * GRID + cx;
    int slot = atomicAdd(&cellcnt[c], 1);  // device scope
    if (slot < CAPC)  // statistically unreachable; guards memory safety
      cells[c * CAPC + slot] = make_float4(x, y, z, __int_as_float(i));
  }
  grid.sync();

  // ---- phase 2: scan+rank, one WAVE per query, grid-stride over groups ----
  int w = tid >> 6;
  int lane = tid & 63;
  int G = m / 4;  // query groups of 4 (one per wave)
  for (int v = blockIdx.x; v < G; v += gridDim.x) {
    int q = v * 4 + w;
    float qx = qry[3 * q], qy = qry[3 * q + 1], qz = qry[3 * q + 2];

    int x0 = max(0, (int)floorf((qx - RM) * (float)GRID));
    int x1 = min(GRID - 1, (int)floorf((qx + RM) * (float)GRID));
    int y0 = max(0, (int)floorf((qy - RM) * (float)GRID));
    int y1 = min(GRID - 1, (int)floorf((qy + RM) * (float)GRID));
    int z0 = max(0, (int)floorf((qz - RM) * (float)GRID));
    int z1 = min(GRID - 1, (int)floorf((qz + RM) * (float)GRID));

    // Parallel row-table build: lane l < nr owns row l (<=3 bins each).
    int ny = y1 - y0 + 1;
    int nx = x1 - x0 + 1;            // 1..3
    int nr = (z1 - z0 + 1) * ny;     // <= 9, wave-uniform
    int base = 0, n0 = 0, n1 = 0, n2 = 0;
    if (lane < nr) {
      int zz = z0 + lane / ny;
      int yy = y0 + lane % ny;
      int rb = (zz * GRID + yy) * GRID + x0;
      base = rb * CAPC;
      n0 = min(cellcnt[rb], CAPC);
      if (nx > 1) n1 = min(cellcnt[rb + 1], CAPC);
      if (nx > 2) n2 = min(cellcnt[rb + 2], CAPC);
    }
    int len = n0 + n1 + n2;
    int pfx = len;                   // inclusive prefix over lanes (nr<=9)
#pragma unroll
    for (int d = 1; d <= 8; d <<= 1) {
      int vv = __shfl_up(pfx, d);
      if (lane >= d) pfx += vv;
    }
    int tot = __shfl(pfx, nr - 1);   // wave-uniform total candidate count
    if (lane < nr) {
      sbase[w][lane] = base;
      sn0[w][lane] = n0;
      sn01[w][lane] = n0 + n1;
      sracc[w][lane] = pfx - len;    // exclusive prefix
    }

    // Flat sweep, UNIFORM trip count: all lanes see every ballot round.
    int nc = 0;
    for (int tb = 0; tb < tot; tb += 64) {
      int t = tb + lane;
      bool hit = false;
      float d2 = 0.f;
      int id = 0;
      if (t < tot) {
        int r = 0;
#pragma unroll
        for (int s = 1; s < 9; ++s)
          if (s < nr && t >= sracc[w][s]) r = s;
        int off = t - sracc[w][r];
        int a0 = sn0[w][r], a01 = sn01[w][r];
        int add = 0;
        if (off >= a0)  add = CAPC - a0;
        if (off >= a01) add = 2 * CAPC - a01;
        float4 P = cells[sbase[w][r] + off + add];
        float dx = qx - P.x;
        float dy = qy - P.y;
        float dz = qz - P.z;
        d2 = dx * dx + dy * dy + dz * dz;  // contract OFF, matches ref
        id = __float_as_int(P.w);
        hit = d2 <= R2;
      }
      unsigned long long b = __ballot(hit);
      int pre = __builtin_amdgcn_mbcnt_hi(
          (unsigned)(b >> 32), __builtin_amdgcn_mbcnt_lo((unsigned)b, 0));
      int slot = nc + pre;
      if (hit && slot < CAP) {
        skey[w][slot] =
            ((unsigned long long)(unsigned)__float_as_int(d2) << 32) |
            (unsigned)id;
      }
      nc += __popcll(b);
    }

    if (lane == 0) cnt[q] = nc;  // raw count; splits clamps to 64
    souts[w][lane] = -1;

    int ncc = nc < CAP ? nc : CAP;
    for (int c = lane; c < ncc; c += 64) {
      unsigned long long mykey = skey[w][c];
      int rank = 0;
#pragma unroll 8
      for (int j = 0; j < ncc; ++j)  // independent ds_read_b64s -> pipelined
        rank += (skey[w][j] < mykey);
      if (rank < MAXNB) souts[w][rank] = (int)(unsigned)mykey;
    }

    nbr[(size_t)q * MAXNB + lane] = souts[w][lane];
  }
  grid.sync();

  // ---- phase 3: row_splits = [0, cumsum(min(cnt,64))] (block 0 only) ----
  if (blockIdx.x == 0) {
    int t = tid;
    int per = m / 256;  // 64
    int base = t * per;
    const int4* c4 = (const int4*)(cnt + base);
    int s = 0;
    for (int i = 0; i < per / 4; ++i) {
      int4 v = c4[i];
      s += min(v.x, MAXNB) + min(v.y, MAXNB) + min(v.z, MAXNB) + min(v.w, MAXNB);
    }
    part[t] = s;
    __syncthreads();
    for (int off = 1; off < 256; off <<= 1) {
      int v = (t >= off) ? part[t - off] : 0;
      __syncthreads();
      part[t] += v;
      __syncthreads();
    }
    int run = (t == 0) ? 0 : part[t - 1];
    if (t == 0) rs[0] = 0;
    for (int i = 0; i < per / 4; ++i) {
      int4 v = c4[i];
      run += min(v.x, MAXNB); rs[base + 4 * i + 1] = run;
      run += min(v.y, MAXNB); rs[base + 4 * i + 2] = run;
      run += min(v.z, MAXNB); rs[base + 4 * i + 3] = run;
      run += min(v.w, MAXNB); rs[base + 4 * i + 4] = run;
    }
  }
}

// ---------------------------------------------------------------------------
extern "C" void kernel_launch(void* const* d_in, const int* in_sizes, int n_in,
                              void* d_out, int out_size, void* d_ws, size_t ws_size,
                              hipStream_t stream) {
  const float* inp = (const float*)d_in[0];  // inp_positions [N,3]
  const float* qry = (const float*)d_in[1];  // out_positions [M,3]
  int n = in_sizes[0] / 3;
  int m = in_sizes[1] / 3;

  char* ws = (char*)d_ws;
  size_t off = 0;
  float4* cells = (float4*)(ws + off); off += (size_t)NCELL * CAPC * 16;
  int* cnt      = (int*)(ws + off);    off += (size_t)m * 4;
  int* cellcnt  = (int*)(ws + off);    off += (size_t)NCELL * 4;

  int* nbr = (int*)d_out;             // [m, 64]
  int* rs = nbr + (size_t)m * MAXNB;  // [m+1]

  // Co-resident grid for cooperative launch: occupancy x 256 CUs, capped.
  int maxb = 4;
  hipOccupancyMaxActiveBlocksPerMultiprocessor(&maxb, fused_kernel, 256, 0);
  if (maxb < 1) maxb = 1;
  int gridsz = maxb * 256;
  if (gridsz > 1024) gridsz = 1024;

  void* args[] = {(void*)&inp, (void*)&qry, (void*)&cellcnt, (void*)&cells,
                  (void*)&cnt, (void*)&nbr, (void*)&rs, (void*)&n, (void*)&m};
  hipLaunchCooperativeKernel(fused_kernel, dim3(gridsz), dim3(256), args, 0,
                             stream);
}

// Round 16
// 86.718 us; speedup vs baseline: 4.1728x; 4.1728x over previous
//
#include <hip/hip_runtime.h>

#define MAXNB 64
#define CAP   128   // candidate capacity per query (expected ~35, max ~65)
#define GRID  12    // 12^3 cells, cell width 1/12 ~ 0.0833 > r = 0.08
#define NCELL (GRID * GRID * GRID)   // 1728
#define CAPC  40    // bin capacity; Poisson(9.48) P(>=40) ~ 1e-15 -> never hit

// ---------------------------------------------------------------------------
// K1: bin points directly into fixed-capacity cells (one pass, no sort).
// cells[c*CAPC + slot] = (x,y,z,idx). Replaces build+cellscan+scatter.
// ---------------------------------------------------------------------------
__global__ __launch_bounds__(256) void buildbin_kernel(
    const float* __restrict__ inp, int* __restrict__ cellcnt,
    float4* __restrict__ cells, int n) {
  int i = blockIdx.x * 256 + threadIdx.x;
  if (i < n) {
    float x = inp[3 * i], y = inp[3 * i + 1], z = inp[3 * i + 2];
    int cx = min(GRID - 1, max(0, (int)(x * (float)GRID)));
    int cy = min(GRID - 1, max(0, (int)(y * (float)GRID)));
    int cz = min(GRID - 1, max(0, (int)(z * (float)GRID)));
    int c = (cz * GRID + cy) * GRID + cx;
    int slot = atomicAdd(&cellcnt[c], 1);
    if (slot < CAPC)  // statistically unreachable; guards memory safety
      cells[c * CAPC + slot] = make_float4(x, y, z, __int_as_float(i));
  }
}

// ---------------------------------------------------------------------------
// K2: fused scan+rank, one WAVE per query, no block barriers, no device-scope
// sync (R8/R15 lesson: in-kernel global sync >> dispatch-boundary cost on
// CDNA4). The <=9 (z,y) rows each cover <=3 x-adjacent bins; lane l<nr loads
// its row's bin counts in parallel, row lengths prefix-summed via shfl_up.
// Flat sweep with UNIFORM trip count (all lanes see every ballot -> nc
// wave-uniform); flat index -> (row via 8-step search, bin via 2 selects).
// Hits compacted via ballot+mbcnt into packed u64 keys (f32bits(d2)<<32|idx);
// rank = count of smaller keys == top_k(-d2) order incl. stable tie-break.
// d2 contract-OFF, bit-identical to the reference.
// ---------------------------------------------------------------------------
__global__ __launch_bounds__(256) void scanrank_kernel(
    const float4* __restrict__ cells, const int* __restrict__ cellcnt,
    const float* __restrict__ qry, int* __restrict__ cnt,
    int* __restrict__ nbr) {
#pragma clang fp contract(off)
  const float R2 = (float)(0.08 * 0.08);
  const float RM = 0.0801f;  // margin 1e-4 >> fp error, << cell slack 0.0033
  __shared__ unsigned long long skey[4][CAP];
  __shared__ int sbase[4][9];   // row first-bin base address (elements)
  __shared__ int sn0[4][9];     // row bin0 count
  __shared__ int sn01[4][9];    // row bin0+bin1 count
  __shared__ int sracc[4][9];   // exclusive prefix of row lengths
  __shared__ int souts[4][MAXNB];
  int w = threadIdx.x >> 6;
  int lane = threadIdx.x & 63;
  int q = blockIdx.x * 4 + w;
  float qx = qry[3 * q], qy = qry[3 * q + 1], qz = qry[3 * q + 2];  // uniform

  int x0 = max(0, (int)floorf((qx - RM) * (float)GRID));
  int x1 = min(GRID - 1, (int)floorf((qx + RM) * (float)GRID));
  int y0 = max(0, (int)floorf((qy - RM) * (float)GRID));
  int y1 = min(GRID - 1, (int)floorf((qy + RM) * (float)GRID));
  int z0 = max(0, (int)floorf((qz - RM) * (float)GRID));
  int z1 = min(GRID - 1, (int)floorf((qz + RM) * (float)GRID));

  // Parallel row-table build: lane l < nr owns row l (<=3 bins each).
  int ny = y1 - y0 + 1;
  int nx = x1 - x0 + 1;            // 1..3
  int nr = (z1 - z0 + 1) * ny;     // <= 9, wave-uniform
  int base = 0, n0 = 0, n1 = 0, n2 = 0;
  if (lane < nr) {
    int zz = z0 + lane / ny;
    int yy = y0 + lane % ny;
    int rb = (zz * GRID + yy) * GRID + x0;
    base = rb * CAPC;
    n0 = min(cellcnt[rb], CAPC);
    if (nx > 1) n1 = min(cellcnt[rb + 1], CAPC);
    if (nx > 2) n2 = min(cellcnt[rb + 2], CAPC);
  }
  int len = n0 + n1 + n2;
  int pfx = len;                   // inclusive prefix over lanes (nr<=9)
#pragma unroll
  for (int d = 1; d <= 8; d <<= 1) {
    int v = __shfl_up(pfx, d);
    if (lane >= d) pfx += v;
  }
  int tot = __shfl(pfx, nr - 1);   // wave-uniform total candidate count
  if (lane < nr) {
    sbase[w][lane] = base;
    sn0[w][lane] = n0;
    sn01[w][lane] = n0 + n1;
    sracc[w][lane] = pfx - len;    // exclusive prefix
  }

  // Flat sweep, UNIFORM trip count: all lanes execute every ballot round.
  int nc = 0;
  for (int tb = 0; tb < tot; tb += 64) {
    int t = tb + lane;
    bool hit = false;
    float d2 = 0.f;
    int id = 0;
    if (t < tot) {
      int r = 0;
#pragma unroll
      for (int s = 1; s < 9; ++s)
        if (s < nr && t >= sracc[w][s]) r = s;
      int off = t - sracc[w][r];
      int a0 = sn0[w][r], a01 = sn01[w][r];
      int add = 0;
      if (off >= a0)  add = CAPC - a0;
      if (off >= a01) add = 2 * CAPC - a01;
      float4 P = cells[sbase[w][r] + off + add];
      float dx = qx - P.x;
      float dy = qy - P.y;
      float dz = qz - P.z;
      d2 = dx * dx + dy * dy + dz * dz;  // contract OFF, matches ref
      id = __float_as_int(P.w);
      hit = d2 <= R2;
    }
    unsigned long long b = __ballot(hit);
    int pre = __builtin_amdgcn_mbcnt_hi(
        (unsigned)(b >> 32), __builtin_amdgcn_mbcnt_lo((unsigned)b, 0));
    int slot = nc + pre;
    if (hit && slot < CAP) {
      skey[w][slot] =
          ((unsigned long long)(unsigned)__float_as_int(d2) << 32) |
          (unsigned)id;
    }
    nc += __popcll(b);
  }

  if (lane == 0) cnt[q] = nc;  // raw count; splits clamps to 64
  souts[w][lane] = -1;

  int ncc = nc < CAP ? nc : CAP;
  for (int c = lane; c < ncc; c += 64) {
    unsigned long long mykey = skey[w][c];
    int rank = 0;
#pragma unroll 8
    for (int j = 0; j < ncc; ++j)  // independent ds_read_b64s -> pipelined
      rank += (skey[w][j] < mykey);
    if (rank < MAXNB) souts[w][rank] = (int)(unsigned)mykey;
  }

  nbr[(size_t)q * MAXNB + lane] = souts[w][lane];
}

// ---------------------------------------------------------------------------
// K3: row_splits = [0, cumsum(min(cnt,64))]. Single block, int4 loads.
// ---------------------------------------------------------------------------
__global__ __launch_bounds__(256) void splits_kernel(
    const int* __restrict__ cnt, int* __restrict__ rs, int m) {
  __shared__ int part[256];
  int t = threadIdx.x;
  int per = m / 256;  // 64
  int base = t * per;
  const int4* c4 = (const int4*)(cnt + base);
  int s = 0;
#pragma unroll
  for (int i = 0; i < 16; ++i) {
    int4 v = c4[i];
    s += min(v.x, MAXNB) + min(v.y, MAXNB) + min(v.z, MAXNB) + min(v.w, MAXNB);
  }
  part[t] = s;
  __syncthreads();
  for (int off = 1; off < 256; off <<= 1) {
    int v = (t >= off) ? part[t - off] : 0;
    __syncthreads();
    part[t] += v;
    __syncthreads();
  }
  int run = (t == 0) ? 0 : part[t - 1];
  if (t == 0) rs[0] = 0;
#pragma unroll
  for (int i = 0; i < 16; ++i) {
    int4 v = c4[i];
    run += min(v.x, MAXNB); rs[base + 4 * i + 1] = run;
    run += min(v.y, MAXNB); rs[base + 4 * i + 2] = run;
    run += min(v.z, MAXNB); rs[base + 4 * i + 3] = run;
    run += min(v.w, MAXNB); rs[base + 4 * i + 4] = run;
  }
}

// ---------------------------------------------------------------------------
extern "C" void kernel_launch(void* const* d_in, const int* in_sizes, int n_in,
                              void* d_out, int out_size, void* d_ws, size_t ws_size,
                              hipStream_t stream) {
  const float* inp = (const float*)d_in[0];  // inp_positions [N,3]
  const float* qry = (const float*)d_in[1];  // out_positions [M,3]
  int n = in_sizes[0] / 3;
  int m = in_sizes[1] / 3;

  char* ws = (char*)d_ws;
  size_t off = 0;
  float4* cells = (float4*)(ws + off); off += (size_t)NCELL * CAPC * 16;
  int* cnt      = (int*)(ws + off);    off += (size_t)m * 4;
  int* cellcnt  = (int*)(ws + off);    off += (size_t)NCELL * 4;  // zeroed

  int* nbr = (int*)d_out;             // [m, 64]
  int* rs = nbr + (size_t)m * MAXNB;  // [m+1]

  hipMemsetAsync(cellcnt, 0, (size_t)NCELL * 4, stream);

  hipLaunchKernelGGL(buildbin_kernel, dim3((n + 255) / 256), dim3(256), 0, stream,
                     inp, cellcnt, cells, n);
  hipLaunchKernelGGL(scanrank_kernel, dim3(m / 4), dim3(256), 0, stream,
                     cells, cellcnt, qry, cnt, nbr);
  hipLaunchKernelGGL(splits_kernel, dim3(1), dim3(256), 0, stream, cnt, rs, m);
}